// Round 1
// baseline (2530.455 us; speedup 1.0000x reference)
//
#include <hip/hip_runtime.h>
#include <math.h>

#define NB 64
#define NP 196
#define ND 256
#define NBP (NB * NP)   // 12544

// ---------------------------------------------------------------------------
// Kernel 1: inverse L2 norms of each token row (1/max(||x||,eps)).
// One wave (64 lanes) per row; float4 loads (16B/lane, coalesced).
// ---------------------------------------------------------------------------
__global__ void filip_norms(const float* __restrict__ t1,
                            const float* __restrict__ t2,
                            float* __restrict__ inv1,
                            float* __restrict__ inv2) {
    int row = blockIdx.x;            // 0 .. 2*NBP-1
    const float* src;
    float* dst;
    int r;
    if (row < NBP) { src = t1; dst = inv1; r = row; }
    else           { src = t2; dst = inv2; r = row - NBP; }
    int lane = threadIdx.x;          // 0..63
    float4 v = reinterpret_cast<const float4*>(src + (size_t)r * ND)[lane];
    float ss = v.x * v.x + v.y * v.y + v.z * v.z + v.w * v.w;
    #pragma unroll
    for (int off = 32; off > 0; off >>= 1)
        ss += __shfl_xor(ss, off, 64);
    if (lane == 0)
        dst[r] = 1.0f / fmaxf(sqrtf(ss), 1e-12f);
}

// ---------------------------------------------------------------------------
// Kernel 2: one block per (b1,b2) pair. Computes the 196x196 sim block in
// fp32 (normalize-on-load), fused reductions:
//   - running row-max/argmax over p2 (registers) -> mean -> sim12[b1][b2]
//   - diag blocks: row argmax -> out idx12, col argmax -> out idx21
// Thread tile: 16x16 threads; thread owns 13 p1-rows (ty+16m) x 4 p2-cols
// (tx+16n) per 64-wide p2 tile. p1 padded 196->208 with zero rows (masked at
// reduction); p2 tail masked by col validity.
// Tie-break: lowest index (matches np.argmax first-occurrence).
// ---------------------------------------------------------------------------
__global__ __launch_bounds__(256)
void filip_sim(const float* __restrict__ t1, const float* __restrict__ t2,
               const float* __restrict__ inv1, const float* __restrict__ inv2,
               float* __restrict__ sim12, float* __restrict__ out)
{
    const int b2 = blockIdx.x, b1 = blockIdx.y;
    const int tid = threadIdx.x;
    const int tx = tid & 15, ty = tid >> 4;
    const bool diag = (b1 == b2);

    __shared__ float As[16][208];   // [k][p1]
    __shared__ float Bs[16][64];    // [k][p2_local]
    __shared__ float colV[16][64];  // diag col-reduce scratch
    __shared__ int   colI[16][64];
    __shared__ float redS[16];

    const float* Ap = t1 + (size_t)b1 * NP * ND;
    const float* Bp = t2 + (size_t)b2 * NP * ND;
    const float* ia = inv1 + b1 * NP;
    const float* ib = inv2 + b2 * NP;

    float rmax[13];
    int   ridx[13];
    #pragma unroll
    for (int m = 0; m < 13; ++m) { rmax[m] = -3.0e38f; ridx[m] = 1 << 30; }

    for (int tile = 0; tile < 4; ++tile) {
        float acc[13][4];
        #pragma unroll
        for (int m = 0; m < 13; ++m)
            #pragma unroll
            for (int n = 0; n < 4; ++n) acc[m][n] = 0.0f;

        for (int kk = 0; kk < 16; ++kk) {
            __syncthreads();   // protect LDS reuse (prev K-step / prev tile)
            // stage A: 208 rows x 16 k  (13 elems/thread)
            #pragma unroll
            for (int i = 0; i < 13; ++i) {
                int e = tid + 256 * i;
                int p1 = e >> 4, k = e & 15;
                float v = 0.0f;
                if (p1 < NP) v = Ap[p1 * ND + kk * 16 + k] * ia[p1];
                As[k][p1] = v;
            }
            // stage B: 64 cols x 16 k (4 elems/thread)
            #pragma unroll
            for (int i = 0; i < 4; ++i) {
                int e = tid + 256 * i;
                int pl = e >> 4, k = e & 15;
                int p2 = tile * 64 + pl;
                float v = 0.0f;
                if (p2 < NP) v = Bp[p2 * ND + kk * 16 + k] * ib[p2];
                Bs[k][pl] = v;
            }
            __syncthreads();
            #pragma unroll 4
            for (int k = 0; k < 16; ++k) {
                float a[13], bq[4];
                #pragma unroll
                for (int m = 0; m < 13; ++m) a[m] = As[k][ty + 16 * m];
                #pragma unroll
                for (int n = 0; n < 4; ++n) bq[n] = Bs[k][tx + 16 * n];
                #pragma unroll
                for (int m = 0; m < 13; ++m)
                    #pragma unroll
                    for (int n = 0; n < 4; ++n)
                        acc[m][n] = fmaf(a[m], bq[n], acc[m][n]);
            }
        }

        // merge this tile's cols into running row-max (mask invalid cols)
        #pragma unroll
        for (int n = 0; n < 4; ++n) {
            int c = tile * 64 + tx + 16 * n;
            if (c < NP) {
                #pragma unroll
                for (int m = 0; m < 13; ++m) {
                    float v = acc[m][n];
                    if (v > rmax[m] || (v == rmax[m] && c < ridx[m])) {
                        rmax[m] = v; ridx[m] = c;
                    }
                }
            }
        }

        if (diag) {
            // per-thread partial col-max over its valid rows
            #pragma unroll
            for (int n = 0; n < 4; ++n) {
                float bv = -3.0e38f; int bi = 1 << 30;
                #pragma unroll
                for (int m = 0; m < 13; ++m) {
                    int row = ty + 16 * m;
                    if (row < NP) {
                        float v = acc[m][n];
                        if (v > bv || (v == bv && row < bi)) { bv = v; bi = row; }
                    }
                }
                colV[ty][tx + 16 * n] = bv;
                colI[ty][tx + 16 * n] = bi;
            }
            __syncthreads();
            if (tid < 64) {
                int c = tile * 64 + tid;
                if (c < NP) {
                    float bv = -3.0e38f; int bi = 1 << 30;
                    #pragma unroll
                    for (int y = 0; y < 16; ++y) {
                        float v = colV[y][tid]; int i2 = colI[y][tid];
                        if (v > bv || (v == bv && i2 < bi)) { bv = v; bi = i2; }
                    }
                    out[1 + NBP + b1 * NP + c] = (float)bi;  // idx_to_keep2_1
                }
            }
        }
        __syncthreads();   // all reads of As/Bs/colV done before next tile
    }

    // cross-tx butterfly reduce of row-max/argmax (width-16 groups = fixed ty)
    #pragma unroll
    for (int m = 0; m < 13; ++m) {
        float v = rmax[m]; int ix = ridx[m];
        #pragma unroll
        for (int off = 1; off < 16; off <<= 1) {
            float ov = __shfl_xor(v, off, 16);
            int   oi = __shfl_xor(ix, off, 16);
            if (ov > v || (ov == v && oi < ix)) { v = ov; ix = oi; }
        }
        rmax[m] = v; ridx[m] = ix;
    }

    if (tx == 0) {
        float s = 0.0f;
        #pragma unroll
        for (int m = 0; m < 13; ++m) {
            int row = ty + 16 * m;
            if (row < NP) {
                s += rmax[m];
                if (diag) out[1 + b1 * NP + row] = (float)ridx[m]; // idx_to_keep1_2
            }
        }
        redS[ty] = s;
    }
    __syncthreads();
    if (tid == 0) {
        float s = 0.0f;
        #pragma unroll
        for (int y = 0; y < 16; ++y) s += redS[y];
        sim12[b1 * NB + b2] = s / 196.0f;
    }
}

// ---------------------------------------------------------------------------
// Kernel 3: InfoNCE loss from sim12[64][64]. One wave; thread i = row i.
// loss = mean_i( logsumexp_j(sim12[i][j]/T) - sim12[i][i]/T )
// ---------------------------------------------------------------------------
__global__ void filip_loss(const float* __restrict__ sim12,
                           float* __restrict__ out) {
    int i = threadIdx.x;  // 0..63
    const float* row = sim12 + i * NB;
    float mx = -3.0e38f;
    for (int j = 0; j < NB; ++j) mx = fmaxf(mx, row[j] / 0.1f);
    float s = 0.0f;
    for (int j = 0; j < NB; ++j) s += expf(row[j] / 0.1f - mx);
    float lse = mx + logf(s);
    float li = lse - row[i] / 0.1f;
    #pragma unroll
    for (int off = 32; off > 0; off >>= 1)
        li += __shfl_xor(li, off, 64);
    if (i == 0) out[0] = li / 64.0f;
}

// ---------------------------------------------------------------------------
extern "C" void kernel_launch(void* const* d_in, const int* in_sizes, int n_in,
                              void* d_out, int out_size, void* d_ws, size_t ws_size,
                              hipStream_t stream) {
    const float* t1 = (const float*)d_in[0];
    const float* t2 = (const float*)d_in[1];
    // d_in[2] (labels) and d_in[3] (epoch) are unused by the reference math.
    float* out = (float*)d_out;
    float* ws  = (float*)d_ws;

    float* inv1  = ws;               // NBP floats
    float* inv2  = ws + NBP;         // NBP floats
    float* sim12 = ws + 2 * NBP;     // NB*NB floats

    filip_norms<<<2 * NBP, 64, 0, stream>>>(t1, t2, inv1, inv2);
    filip_sim<<<dim3(NB, NB), 256, 0, stream>>>(t1, t2, inv1, inv2, sim12, out);
    filip_loss<<<1, 64, 0, stream>>>(sim12, out);
}

// Round 2
// 614.045 us; speedup vs baseline: 4.1210x; 4.1210x over previous
//
#include <hip/hip_runtime.h>
#include <math.h>

#define NB 64
#define NP 196
#define ND 256
#define NBP (NB * NP)   // 12544

typedef __bf16 v8bf __attribute__((ext_vector_type(8)));
typedef float f32x16 __attribute__((ext_vector_type(16)));

// ---------------------------------------------------------------------------
// Kernel 1: inverse L2 norms (1/max(||x||,eps)); also zeroes sim12 (first 64
// blocks) so no memset is needed inside graph capture.
// ---------------------------------------------------------------------------
__global__ void filip_norms(const float* __restrict__ t1,
                            const float* __restrict__ t2,
                            float* __restrict__ inv1,
                            float* __restrict__ inv2,
                            float* __restrict__ sim12) {
    int row = blockIdx.x;            // 0 .. 2*NBP-1
    int lane = threadIdx.x;          // 0..63
    if (row < NB) sim12[row * NB + lane] = 0.0f;   // zero 64x64 accumulator
    const float* src; float* dst; int r;
    if (row < NBP) { src = t1; dst = inv1; r = row; }
    else           { src = t2; dst = inv2; r = row - NBP; }
    float4 v = reinterpret_cast<const float4*>(src + (size_t)r * ND)[lane];
    float ss = v.x * v.x + v.y * v.y + v.z * v.z + v.w * v.w;
    #pragma unroll
    for (int off = 32; off > 0; off >>= 1)
        ss += __shfl_xor(ss, off, 64);
    if (lane == 0)
        dst[r] = 1.0f / fmaxf(sqrtf(ss), 1e-12f);
}

// ---------------------------------------------------------------------------
// Kernel 2 (MFMA): sim12[b1][b2] = sum over p1 of max_{p2} sim, in bf16 MFMA.
// Block = 128 rows (global p1-rows) x 256 cols (one b2, p2 padded 196->256
// with zero rows => padded sims = 0, never the max since true rowmax > 0
// w.h.p. for random-normal data). 4 waves, wave tile 64x128 = 2x4 MFMA tiles
// of 32x32x16. LDS [row][k] bf16, G4 XOR swizzle byte^=(row&7)<<4 on both
// ds_write_b128 and ds_read_b128.
// ---------------------------------------------------------------------------
__device__ __forceinline__ v8bf cvt8(float4 a, float4 b, float s) {
    v8bf v;
    v[0] = (__bf16)(a.x * s); v[1] = (__bf16)(a.y * s);
    v[2] = (__bf16)(a.z * s); v[3] = (__bf16)(a.w * s);
    v[4] = (__bf16)(b.x * s); v[5] = (__bf16)(b.y * s);
    v[6] = (__bf16)(b.z * s); v[7] = (__bf16)(b.w * s);
    return v;
}

#define BM 128
#define BN 256
#define BK 64

__global__ __launch_bounds__(256, 2)
void filip_mfma(const float* __restrict__ t1, const float* __restrict__ t2,
                const float* __restrict__ inv1, const float* __restrict__ inv2,
                float* __restrict__ sim12)
{
    __shared__ unsigned short Asb[BM * BK];   // 16 KB, swizzled [row][k]
    __shared__ unsigned short Bsb[BN * BK];   // 32 KB
    __shared__ float rmx[2][BM];

    const int bRow = blockIdx.x;   // 0..97
    const int b2   = blockIdx.y;   // 0..63
    const int tid  = threadIdx.x;
    const int lane = tid & 63, wave = tid >> 6;
    const int wr = wave >> 1, wc = wave & 1;
    const int ln = lane & 31, hi = lane >> 5;

    const float* Abase = t1 + (size_t)bRow * BM * ND;
    const float* Bbase = t2 + (size_t)b2 * NP * ND;

    f32x16 acc[2][4];
    #pragma unroll
    for (int mt = 0; mt < 2; ++mt)
        #pragma unroll
        for (int nt = 0; nt < 4; ++nt)
            #pragma unroll
            for (int r = 0; r < 16; ++r) acc[mt][nt][r] = 0.0f;

    for (int kc = 0; kc < 4; ++kc) {
        __syncthreads();   // previous chunk's reads complete before overwrite
        // ---- stage A: 128 rows x 64 k (8 bf16/thread/iter, 4 iters) ----
        #pragma unroll
        for (int i = 0; i < 4; ++i) {
            int flat = (i * 256 + tid) * 8;
            int r = flat >> 6, k0 = flat & 63;
            const float* gp = Abase + (size_t)r * ND + kc * BK + k0;
            float4 f0 = *reinterpret_cast<const float4*>(gp);
            float4 f1 = *reinterpret_cast<const float4*>(gp + 4);
            float s = inv1[bRow * BM + r];
            v8bf v = cvt8(f0, f1, s);
            int off = r * 128 + ((k0 * 2) ^ ((r & 7) << 4));
            *reinterpret_cast<v8bf*>(reinterpret_cast<char*>(Asb) + off) = v;
        }
        // ---- stage B: 256 rows (196 real + 60 zero) x 64 k, 8 iters ----
        #pragma unroll
        for (int i = 0; i < 8; ++i) {
            int flat = (i * 256 + tid) * 8;
            int r = flat >> 6, k0 = flat & 63;
            v8bf v;
            if (r < NP) {
                const float* gp = Bbase + (size_t)r * ND + kc * BK + k0;
                float4 f0 = *reinterpret_cast<const float4*>(gp);
                float4 f1 = *reinterpret_cast<const float4*>(gp + 4);
                float s = inv2[b2 * NP + r];
                v = cvt8(f0, f1, s);
            } else {
                #pragma unroll
                for (int j = 0; j < 8; ++j) v[j] = (__bf16)0.0f;
            }
            int off = r * 128 + ((k0 * 2) ^ ((r & 7) << 4));
            *reinterpret_cast<v8bf*>(reinterpret_cast<char*>(Bsb) + off) = v;
        }
        __syncthreads();
        // ---- compute: 4 k-steps of K=16 ----
        #pragma unroll
        for (int ks = 0; ks < 4; ++ks) {
            const int kb = ks * 32 + hi * 16;   // byte col in LDS row
            v8bf af[2], bfr[4];
            #pragma unroll
            for (int mt = 0; mt < 2; ++mt) {
                int r = wr * 64 + mt * 32 + ln;
                af[mt] = *reinterpret_cast<const v8bf*>(
                    reinterpret_cast<const char*>(Asb) + r * 128 + (kb ^ ((r & 7) << 4)));
            }
            #pragma unroll
            for (int nt = 0; nt < 4; ++nt) {
                int c = wc * 128 + nt * 32 + ln;
                bfr[nt] = *reinterpret_cast<const v8bf*>(
                    reinterpret_cast<const char*>(Bsb) + c * 128 + (kb ^ ((c & 7) << 4)));
            }
            #pragma unroll
            for (int mt = 0; mt < 2; ++mt)
                #pragma unroll
                for (int nt = 0; nt < 4; ++nt)
                    acc[mt][nt] = __builtin_amdgcn_mfma_f32_32x32x16_bf16(
                        af[mt], bfr[nt], acc[mt][nt], 0, 0, 0);
        }
    }

    // ---- fused rowmax: max over 4 n-tiles, then butterfly over 32 cols ----
    // C/D layout (verified): col = lane&31, row = (r&3) + 8*(r>>2) + 4*hi
    #pragma unroll
    for (int mt = 0; mt < 2; ++mt) {
        float t[16];
        #pragma unroll
        for (int r = 0; r < 16; ++r) {
            float m = fmaxf(fmaxf(acc[mt][0][r], acc[mt][1][r]),
                            fmaxf(acc[mt][2][r], acc[mt][3][r]));
            #pragma unroll
            for (int off = 1; off <= 16; off <<= 1)
                m = fmaxf(m, __shfl_xor(m, off, 64));
            t[r] = m;
        }
        if (ln == 0) {
            #pragma unroll
            for (int r = 0; r < 16; ++r) {
                int row = wr * 64 + mt * 32 + (r & 3) + 8 * (r >> 2) + 4 * hi;
                rmx[wc][row] = t[r];
            }
        }
    }
    __syncthreads();
    // ---- merge wc halves, segmented sum by b1, 2 atomics per wave ----
    if (tid < BM) {
        float m = fmaxf(rmx[0][tid], rmx[1][tid]);
        int grow = bRow * BM + tid;
        int b1 = grow / NP;
        int fb = (bRow * BM) / NP;
        float v0 = (b1 == fb) ? m : 0.0f;
        float v1 = (b1 != fb) ? m : 0.0f;
        #pragma unroll
        for (int off = 1; off < 64; off <<= 1) {
            v0 += __shfl_xor(v0, off, 64);
            v1 += __shfl_xor(v1, off, 64);
        }
        if (lane == 0) {
            atomicAdd(&sim12[fb * NB + b2], v0);
            int lb = (bRow * BM + BM - 1) / NP;
            if (lb != fb) atomicAdd(&sim12[lb * NB + b2], v1);
        }
    }
}

// ---------------------------------------------------------------------------
// Kernel 3 (fp32, exact): diagonal blocks only -> argmax indices. Arithmetic
// order identical to the round-1 passing kernel (fma over k ascending), so
// indices stay bit-exact vs numpy. LDS strides padded (209/65) => 16 distinct
// banks for the 16-lane k-groups (was 8/16-way conflicted).
// ---------------------------------------------------------------------------
__global__ __launch_bounds__(256)
void filip_diag(const float* __restrict__ t1, const float* __restrict__ t2,
                const float* __restrict__ inv1, const float* __restrict__ inv2,
                float* __restrict__ out)
{
    const int b = blockIdx.x;          // b1 == b2 == b
    const int tid = threadIdx.x;
    const int tx = tid & 15, ty = tid >> 4;

    __shared__ float As[16][209];
    __shared__ float Bs[16][65];
    __shared__ float colV[16][65];
    __shared__ int   colI[16][65];

    const float* Ap = t1 + (size_t)b * NP * ND;
    const float* Bp = t2 + (size_t)b * NP * ND;
    const float* ia = inv1 + b * NP;
    const float* ib = inv2 + b * NP;

    float rmax[13];
    int   ridx[13];
    #pragma unroll
    for (int m = 0; m < 13; ++m) { rmax[m] = -3.0e38f; ridx[m] = 1 << 30; }

    for (int tile = 0; tile < 4; ++tile) {
        float acc[13][4];
        #pragma unroll
        for (int m = 0; m < 13; ++m)
            #pragma unroll
            for (int n = 0; n < 4; ++n) acc[m][n] = 0.0f;

        for (int kk = 0; kk < 16; ++kk) {
            __syncthreads();
            #pragma unroll
            for (int i = 0; i < 13; ++i) {
                int e = tid + 256 * i;
                int p1 = e >> 4, k = e & 15;
                float v = 0.0f;
                if (p1 < NP) v = Ap[p1 * ND + kk * 16 + k] * ia[p1];
                As[k][p1] = v;
            }
            #pragma unroll
            for (int i = 0; i < 4; ++i) {
                int e = tid + 256 * i;
                int pl = e >> 4, k = e & 15;
                int p2 = tile * 64 + pl;
                float v = 0.0f;
                if (p2 < NP) v = Bp[p2 * ND + kk * 16 + k] * ib[p2];
                Bs[k][pl] = v;
            }
            __syncthreads();
            #pragma unroll 4
            for (int k = 0; k < 16; ++k) {
                float a[13], bq[4];
                #pragma unroll
                for (int m = 0; m < 13; ++m) a[m] = As[k][ty + 16 * m];
                #pragma unroll
                for (int n = 0; n < 4; ++n) bq[n] = Bs[k][tx + 16 * n];
                #pragma unroll
                for (int m = 0; m < 13; ++m)
                    #pragma unroll
                    for (int n = 0; n < 4; ++n)
                        acc[m][n] = fmaf(a[m], bq[n], acc[m][n]);
            }
        }

        #pragma unroll
        for (int n = 0; n < 4; ++n) {
            int c = tile * 64 + tx + 16 * n;
            if (c < NP) {
                #pragma unroll
                for (int m = 0; m < 13; ++m) {
                    float v = acc[m][n];
                    if (v > rmax[m] || (v == rmax[m] && c < ridx[m])) {
                        rmax[m] = v; ridx[m] = c;
                    }
                }
            }
        }

        // col argmax (idx_to_keep2_1)
        #pragma unroll
        for (int n = 0; n < 4; ++n) {
            float bv = -3.0e38f; int bi = 1 << 30;
            #pragma unroll
            for (int m = 0; m < 13; ++m) {
                int row = ty + 16 * m;
                if (row < NP) {
                    float v = acc[m][n];
                    if (v > bv || (v == bv && row < bi)) { bv = v; bi = row; }
                }
            }
            colV[ty][tx + 16 * n] = bv;
            colI[ty][tx + 16 * n] = bi;
        }
        __syncthreads();
        if (tid < 64) {
            int c = tile * 64 + tid;
            if (c < NP) {
                float bv = -3.0e38f; int bi = 1 << 30;
                #pragma unroll
                for (int y = 0; y < 16; ++y) {
                    float v = colV[y][tid]; int i2 = colI[y][tid];
                    if (v > bv || (v == bv && i2 < bi)) { bv = v; bi = i2; }
                }
                out[1 + NBP + b * NP + c] = (float)bi;
            }
        }
        __syncthreads();
    }

    // row argmax (idx_to_keep1_2)
    #pragma unroll
    for (int m = 0; m < 13; ++m) {
        float v = rmax[m]; int ix = ridx[m];
        #pragma unroll
        for (int off = 1; off < 16; off <<= 1) {
            float ov = __shfl_xor(v, off, 16);
            int   oi = __shfl_xor(ix, off, 16);
            if (ov > v || (ov == v && oi < ix)) { v = ov; ix = oi; }
        }
        rmax[m] = v; ridx[m] = ix;
    }
    if (tx == 0) {
        #pragma unroll
        for (int m = 0; m < 13; ++m) {
            int row = ty + 16 * m;
            if (row < NP) out[1 + b * NP + row] = (float)ridx[m];
        }
    }
}

// ---------------------------------------------------------------------------
// Kernel 4: InfoNCE loss. sim12 holds SUMS of rowmax -> scale by 10/196.
// ---------------------------------------------------------------------------
__global__ void filip_loss(const float* __restrict__ sim12,
                           float* __restrict__ out) {
    int i = threadIdx.x;  // 0..63
    const float SC = 10.0f / 196.0f;
    const float* row = sim12 + i * NB;
    float mx = -3.0e38f;
    for (int j = 0; j < NB; ++j) mx = fmaxf(mx, row[j] * SC);
    float s = 0.0f;
    for (int j = 0; j < NB; ++j) s += expf(row[j] * SC - mx);
    float lse = mx + logf(s);
    float li = lse - row[i] * SC;
    #pragma unroll
    for (int off = 32; off > 0; off >>= 1)
        li += __shfl_xor(li, off, 64);
    if (i == 0) out[0] = li / 64.0f;
}

// ---------------------------------------------------------------------------
extern "C" void kernel_launch(void* const* d_in, const int* in_sizes, int n_in,
                              void* d_out, int out_size, void* d_ws, size_t ws_size,
                              hipStream_t stream) {
    const float* t1 = (const float*)d_in[0];
    const float* t2 = (const float*)d_in[1];
    float* out = (float*)d_out;
    float* ws  = (float*)d_ws;

    float* inv1  = ws;               // NBP floats
    float* inv2  = ws + NBP;         // NBP floats
    float* sim12 = ws + 2 * NBP;     // NB*NB floats

    filip_norms<<<2 * NBP, 64, 0, stream>>>(t1, t2, inv1, inv2, sim12);
    filip_mfma<<<dim3(98, NB), 256, 0, stream>>>(t1, t2, inv1, inv2, sim12);
    filip_diag<<<NB, 256, 0, stream>>>(t1, t2, inv1, inv2, out);
    filip_loss<<<1, 64, 0, stream>>>(sim12, out);
}

// Round 3
// 220.396 us; speedup vs baseline: 11.4814x; 2.7861x over previous
//
#include <hip/hip_runtime.h>
#include <math.h>

#define NB 64
#define NP 196
#define ND 256
#define NBP (NB * NP)   // 12544

typedef __bf16 v8bf __attribute__((ext_vector_type(8)));
typedef __bf16 v4bf __attribute__((ext_vector_type(4)));
typedef float f32x16 __attribute__((ext_vector_type(16)));

// ws layout (fast path), bytes:
//   inv1   @ 0          : 12544 f32
//   inv2   @ 50176      : 12544 f32
//   sim12  @ 100352     : 4096  f32
//   t1bf   @ 116736     : 12544*256 bf16 = 6422528 B
//   t2bf   @ 6539264    : 16384*256 bf16 = 8388608 B (p2 padded 196->256, zeros)
//   parts  @ 14927872   : 64*4*196 u64   = 401408 B
#define WS_T1BF   116736
#define WS_T2BF   6539264
#define WS_PARTS  14927872
#define WS_NEED   15329280

// ---------------------------------------------------------------------------
// packed (value,index) for argmax with np first-occurrence tie-break
// ---------------------------------------------------------------------------
__device__ __forceinline__ unsigned int fmono(float v) {
    unsigned int u = __float_as_uint(v);
    return (u & 0x80000000u) ? ~u : (u | 0x80000000u);
}
__device__ __forceinline__ unsigned long long packVI(float v, int idx) {
    return ((unsigned long long)fmono(v) << 32) | (unsigned int)(~idx);
}

// ===========================================================================
// FAST PATH
// ===========================================================================

// Kernel 1: per-row norm -> inv arrays; convert normalized rows to bf16
// (t1bf linear; t2bf padded 256 rows/batch, pad rows zeroed); zero sim12.
__global__ void filip_prep(const float* __restrict__ t1, const float* __restrict__ t2,
                           float* __restrict__ inv1, float* __restrict__ inv2,
                           float* __restrict__ sim12,
                           __bf16* __restrict__ t1bf, __bf16* __restrict__ t2bf) {
    int id = blockIdx.x;             // 0 .. NBP + NB*256 - 1
    int lane = threadIdx.x;          // 0..63
    if (id < NB) sim12[id * NB + lane] = 0.0f;
    if (id < NBP) {
        const float* src = t1 + (size_t)id * ND;
        float4 v = reinterpret_cast<const float4*>(src)[lane];
        float ss = v.x * v.x + v.y * v.y + v.z * v.z + v.w * v.w;
        #pragma unroll
        for (int off = 32; off > 0; off >>= 1) ss += __shfl_xor(ss, off, 64);
        float inv = 1.0f / fmaxf(sqrtf(ss), 1e-12f);
        if (lane == 0) inv1[id] = inv;
        v4bf o;
        o[0] = (__bf16)(v.x * inv); o[1] = (__bf16)(v.y * inv);
        o[2] = (__bf16)(v.z * inv); o[3] = (__bf16)(v.w * inv);
        *reinterpret_cast<v4bf*>(t1bf + (size_t)id * ND + 4 * lane) = o;
    } else {
        int pid = id - NBP;          // 0..16383
        int b2 = pid >> 8, p2 = pid & 255;
        __bf16* dst = t2bf + (size_t)pid * ND + 4 * lane;
        if (p2 < NP) {
            const float* src = t2 + (size_t)(b2 * NP + p2) * ND;
            float4 v = reinterpret_cast<const float4*>(src)[lane];
            float ss = v.x * v.x + v.y * v.y + v.z * v.z + v.w * v.w;
            #pragma unroll
            for (int off = 32; off > 0; off >>= 1) ss += __shfl_xor(ss, off, 64);
            float inv = 1.0f / fmaxf(sqrtf(ss), 1e-12f);
            if (lane == 0) inv2[b2 * NP + p2] = inv;
            v4bf o;
            o[0] = (__bf16)(v.x * inv); o[1] = (__bf16)(v.y * inv);
            o[2] = (__bf16)(v.z * inv); o[3] = (__bf16)(v.w * inv);
            *reinterpret_cast<v4bf*>(dst) = o;
        } else {
            v4bf z; z[0] = z[1] = z[2] = z[3] = (__bf16)0.0f;
            *reinterpret_cast<v4bf*>(dst) = z;
        }
    }
}

// Kernel 2: bf16 MFMA mean-of-rowmax. Same compute structure as the passing
// round-2 kernel; staging is now pure 16B bf16 load -> swizzled LDS store.
#define BM 128
#define BN 256
#define BK 64

__global__ __launch_bounds__(256, 2)
void filip_mfma2(const __bf16* __restrict__ t1bf, const __bf16* __restrict__ t2bf,
                 float* __restrict__ sim12)
{
    __shared__ unsigned short Asb[BM * BK];   // 16 KB, swizzled [row][k]
    __shared__ unsigned short Bsb[BN * BK];   // 32 KB
    __shared__ float rmx[2][BM];

    // XCD-aware bijective swizzle: 6272 = 8 * 784 blocks; each XCD gets a
    // contiguous linear range = 8 consecutive b2 panels (1 MB, L2-resident).
    int n = blockIdx.x + 98 * blockIdx.y;
    int w = (n & 7) * 784 + (n >> 3);
    const int bRow = w % 98;
    const int b2   = w / 98;

    const int tid  = threadIdx.x;
    const int lane = tid & 63, wave = tid >> 6;
    const int wr = wave >> 1, wc = wave & 1;
    const int ln = lane & 31, hi = lane >> 5;

    const __bf16* Abase = t1bf + (size_t)bRow * BM * ND;
    const __bf16* Bbase = t2bf + (size_t)b2 * 256 * ND;

    f32x16 acc[2][4];
    #pragma unroll
    for (int mt = 0; mt < 2; ++mt)
        #pragma unroll
        for (int nt = 0; nt < 4; ++nt)
            #pragma unroll
            for (int r = 0; r < 16; ++r) acc[mt][nt][r] = 0.0f;

    for (int kc = 0; kc < 4; ++kc) {
        __syncthreads();
        #pragma unroll
        for (int i = 0; i < 4; ++i) {
            int flat = (i * 256 + tid) * 8;
            int r = flat >> 6, k0 = flat & 63;
            v8bf v = *reinterpret_cast<const v8bf*>(Abase + (size_t)r * ND + kc * BK + k0);
            int off = r * 128 + ((k0 * 2) ^ ((r & 7) << 4));
            *reinterpret_cast<v8bf*>(reinterpret_cast<char*>(Asb) + off) = v;
        }
        #pragma unroll
        for (int i = 0; i < 8; ++i) {
            int flat = (i * 256 + tid) * 8;
            int r = flat >> 6, k0 = flat & 63;
            v8bf v = *reinterpret_cast<const v8bf*>(Bbase + (size_t)r * ND + kc * BK + k0);
            int off = r * 128 + ((k0 * 2) ^ ((r & 7) << 4));
            *reinterpret_cast<v8bf*>(reinterpret_cast<char*>(Bsb) + off) = v;
        }
        __syncthreads();
        #pragma unroll
        for (int ks = 0; ks < 4; ++ks) {
            const int kb = ks * 32 + hi * 16;
            v8bf af[2], bfr[4];
            #pragma unroll
            for (int mt = 0; mt < 2; ++mt) {
                int r = wr * 64 + mt * 32 + ln;
                af[mt] = *reinterpret_cast<const v8bf*>(
                    reinterpret_cast<const char*>(Asb) + r * 128 + (kb ^ ((r & 7) << 4)));
            }
            #pragma unroll
            for (int nt = 0; nt < 4; ++nt) {
                int c = wc * 128 + nt * 32 + ln;
                bfr[nt] = *reinterpret_cast<const v8bf*>(
                    reinterpret_cast<const char*>(Bsb) + c * 128 + (kb ^ ((c & 7) << 4)));
            }
            #pragma unroll
            for (int mt = 0; mt < 2; ++mt)
                #pragma unroll
                for (int nt = 0; nt < 4; ++nt)
                    acc[mt][nt] = __builtin_amdgcn_mfma_f32_32x32x16_bf16(
                        af[mt], bfr[nt], acc[mt][nt], 0, 0, 0);
        }
    }

    // fused rowmax; C/D layout: col = lane&31, row = (r&3) + 8*(r>>2) + 4*hi
    #pragma unroll
    for (int mt = 0; mt < 2; ++mt) {
        float t[16];
        #pragma unroll
        for (int r = 0; r < 16; ++r) {
            float m = fmaxf(fmaxf(acc[mt][0][r], acc[mt][1][r]),
                            fmaxf(acc[mt][2][r], acc[mt][3][r]));
            #pragma unroll
            for (int off = 1; off <= 16; off <<= 1)
                m = fmaxf(m, __shfl_xor(m, off, 64));
            t[r] = m;
        }
        if (ln == 0) {
            #pragma unroll
            for (int r = 0; r < 16; ++r) {
                int row = wr * 64 + mt * 32 + (r & 3) + 8 * (r >> 2) + 4 * hi;
                rmx[wc][row] = t[r];
            }
        }
    }
    __syncthreads();
    if (tid < BM) {
        float m = fmaxf(rmx[0][tid], rmx[1][tid]);
        int grow = bRow * BM + tid;
        int b1 = grow / NP;
        int fb = (bRow * BM) / NP;
        float v0 = (b1 == fb) ? m : 0.0f;
        float v1 = (b1 != fb) ? m : 0.0f;
        #pragma unroll
        for (int off = 1; off < 64; off <<= 1) {
            v0 += __shfl_xor(v0, off, 64);
            v1 += __shfl_xor(v1, off, 64);
        }
        if (lane == 0) {
            atomicAdd(&sim12[fb * NB + b2], v0);
            int lb = (bRow * BM + BM - 1) / NP;
            if (lb != fb) atomicAdd(&sim12[lb * NB + b2], v1);
        }
    }
}

// Kernel 3: fp32-exact diagonal blocks, 4 blocks per batch (49 rows each).
// Thread tile 4 rows x 16 cols (4x float4 groups). Same k-accumulation order
// as the passing round-2 kernel -> bit-identical sims. Row argmax in-wave;
// col argmax via packed u64 partials merged by filip_fin.
__global__ __launch_bounds__(256)
void filip_diag4(const float* __restrict__ t1, const float* __restrict__ t2,
                 const float* __restrict__ inv1, const float* __restrict__ inv2,
                 unsigned long long* __restrict__ parts,
                 float* __restrict__ out)
{
    const int q = blockIdx.x;          // 0..3 (row quarter)
    const int b = blockIdx.y;          // 0..63
    const int r0 = q * 49;
    const int tid = threadIdx.x;
    const int tx = tid & 15, ty = tid >> 4;

    __shared__ float smemF[2176 + 8320];       // As[32][68] + Bs[32][260]
    float* As = smemF;
    float* Bs = smemF + 2176;
    unsigned long long* colP = reinterpret_cast<unsigned long long*>(smemF); // reuse, 32KB

    const float* Ap = t1 + (size_t)b * NP * ND;
    const float* Bp = t2 + (size_t)b * NP * ND;
    const float* ia = inv1 + b * NP;
    const float* ib = inv2 + b * NP;

    float acc[4][4][4];
    #pragma unroll
    for (int i = 0; i < 4; ++i)
        #pragma unroll
        for (int j = 0; j < 4; ++j)
            #pragma unroll
            for (int l = 0; l < 4; ++l) acc[i][j][l] = 0.0f;

    for (int kc = 0; kc < 8; ++kc) {
        __syncthreads();
        // stage A: 64 rows (49 real) x 32 k, transposed to As[k][row]
        #pragma unroll
        for (int i = 0; i < 2; ++i) {
            int f4 = tid + 256 * i;            // 0..511
            int row = f4 >> 3, k4 = f4 & 7;
            float4 v = make_float4(0.f, 0.f, 0.f, 0.f);
            if (row < 49) {
                v = *reinterpret_cast<const float4*>(Ap + (size_t)(r0 + row) * ND + kc * 32 + 4 * k4);
                float s = ia[r0 + row];
                v.x *= s; v.y *= s; v.z *= s; v.w *= s;
            }
            As[(4 * k4 + 0) * 68 + row] = v.x;
            As[(4 * k4 + 1) * 68 + row] = v.y;
            As[(4 * k4 + 2) * 68 + row] = v.z;
            As[(4 * k4 + 3) * 68 + row] = v.w;
        }
        // stage B: 256 cols (196 real) x 32 k, transposed to Bs[k][col]
        #pragma unroll
        for (int i = 0; i < 8; ++i) {
            int f4 = tid + 256 * i;            // 0..2047
            int col = f4 >> 3, k4 = f4 & 7;
            float4 v = make_float4(0.f, 0.f, 0.f, 0.f);
            if (col < NP) {
                v = *reinterpret_cast<const float4*>(Bp + (size_t)col * ND + kc * 32 + 4 * k4);
                float s = ib[col];
                v.x *= s; v.y *= s; v.z *= s; v.w *= s;
            }
            Bs[(4 * k4 + 0) * 260 + col] = v.x;
            Bs[(4 * k4 + 1) * 260 + col] = v.y;
            Bs[(4 * k4 + 2) * 260 + col] = v.z;
            Bs[(4 * k4 + 3) * 260 + col] = v.w;
        }
        __syncthreads();
        #pragma unroll 4
        for (int k = 0; k < 32; ++k) {
            float a0 = As[k * 68 + 4 * ty + 0];
            float a1 = As[k * 68 + 4 * ty + 1];
            float a2 = As[k * 68 + 4 * ty + 2];
            float a3 = As[k * 68 + 4 * ty + 3];
            float4 bq[4];
            #pragma unroll
            for (int j = 0; j < 4; ++j)
                bq[j] = *reinterpret_cast<const float4*>(&Bs[k * 260 + 4 * tx + 64 * j]);
            #pragma unroll
            for (int j = 0; j < 4; ++j) {
                acc[0][j][0] = fmaf(a0, bq[j].x, acc[0][j][0]);
                acc[0][j][1] = fmaf(a0, bq[j].y, acc[0][j][1]);
                acc[0][j][2] = fmaf(a0, bq[j].z, acc[0][j][2]);
                acc[0][j][3] = fmaf(a0, bq[j].w, acc[0][j][3]);
                acc[1][j][0] = fmaf(a1, bq[j].x, acc[1][j][0]);
                acc[1][j][1] = fmaf(a1, bq[j].y, acc[1][j][1]);
                acc[1][j][2] = fmaf(a1, bq[j].z, acc[1][j][2]);
                acc[1][j][3] = fmaf(a1, bq[j].w, acc[1][j][3]);
                acc[2][j][0] = fmaf(a2, bq[j].x, acc[2][j][0]);
                acc[2][j][1] = fmaf(a2, bq[j].y, acc[2][j][1]);
                acc[2][j][2] = fmaf(a2, bq[j].z, acc[2][j][2]);
                acc[2][j][3] = fmaf(a2, bq[j].w, acc[2][j][3]);
                acc[3][j][0] = fmaf(a3, bq[j].x, acc[3][j][0]);
                acc[3][j][1] = fmaf(a3, bq[j].y, acc[3][j][1]);
                acc[3][j][2] = fmaf(a3, bq[j].z, acc[3][j][2]);
                acc[3][j][3] = fmaf(a3, bq[j].w, acc[3][j][3]);
            }
        }
    }

    // row argmax (idx_to_keep1_2): reduce 16 cols/thread then across tx
    #pragma unroll
    for (int i = 0; i < 4; ++i) {
        unsigned long long best = 0ull;
        #pragma unroll
        for (int j = 0; j < 4; ++j)
            #pragma unroll
            for (int l = 0; l < 4; ++l) {
                int c = 64 * j + 4 * tx + l;
                if (c < NP) {
                    unsigned long long p = packVI(acc[i][j][l], c);
                    if (p > best) best = p;
                }
            }
        #pragma unroll
        for (int off = 1; off < 16; off <<= 1) {
            unsigned long long o = __shfl_xor(best, off, 16);
            if (o > best) best = o;
        }
        int rl = 4 * ty + i;
        if (tx == 0 && rl < 49)
            out[1 + b * NP + r0 + rl] = (float)(unsigned int)(~best);
    }

    // col argmax partials (idx_to_keep2_1): per-thread over its 4 rows,
    // cross-ty reduce in LDS, one packed u64 per (b,q,col)
    __syncthreads();
    #pragma unroll
    for (int j = 0; j < 4; ++j)
        #pragma unroll
        for (int l = 0; l < 4; ++l) {
            unsigned long long best = 0ull;
            #pragma unroll
            for (int i = 0; i < 4; ++i) {
                int rl = 4 * ty + i;
                if (rl < 49) {
                    unsigned long long p = packVI(acc[i][j][l], r0 + rl);
                    if (p > best) best = p;
                }
            }
            colP[ty * 256 + 64 * j + 4 * tx + l] = best;
        }
    __syncthreads();
    {
        unsigned long long best = 0ull;
        #pragma unroll
        for (int y = 0; y < 16; ++y) {
            unsigned long long o = colP[y * 256 + tid];
            if (o > best) best = o;
        }
        if (tid < NP) parts[(b * 4 + q) * NP + tid] = best;
    }
}

// Kernel 4: merge the 4 quarter partials -> idx_to_keep2_1
__global__ void filip_fin(const unsigned long long* __restrict__ parts,
                          float* __restrict__ out) {
    int id = blockIdx.x * 256 + threadIdx.x;   // 49*256 = 12544
    int b = id / NP, c = id - b * NP;
    unsigned long long best = 0ull;
    #pragma unroll
    for (int qq = 0; qq < 4; ++qq) {
        unsigned long long o = parts[(b * 4 + qq) * NP + c];
        if (o > best) best = o;
    }
    out[1 + NBP + id] = (float)(unsigned int)(~best);
}

// Kernel 5: InfoNCE loss. sim12 holds SUMS of rowmax -> scale by 10/196.
__global__ void filip_loss(const float* __restrict__ sim12,
                           float* __restrict__ out) {
    int i = threadIdx.x;  // 0..63
    const float SC = 10.0f / 196.0f;
    const float* row = sim12 + i * NB;
    float mx = -3.0e38f;
    for (int j = 0; j < NB; ++j) mx = fmaxf(mx, row[j] * SC);
    float s = 0.0f;
    for (int j = 0; j < NB; ++j) s += expf(row[j] * SC - mx);
    float lse = mx + logf(s);
    float li = lse - row[i] * SC;
    #pragma unroll
    for (int off = 32; off > 0; off >>= 1)
        li += __shfl_xor(li, off, 64);
    if (i == 0) out[0] = li / 64.0f;
}

// ===========================================================================
// FALLBACK PATH (verbatim round-2, known-passing) — used if ws too small
// ===========================================================================
__global__ void filip_norms(const float* __restrict__ t1,
                            const float* __restrict__ t2,
                            float* __restrict__ inv1,
                            float* __restrict__ inv2,
                            float* __restrict__ sim12) {
    int row = blockIdx.x;
    int lane = threadIdx.x;
    if (row < NB) sim12[row * NB + lane] = 0.0f;
    const float* src; float* dst; int r;
    if (row < NBP) { src = t1; dst = inv1; r = row; }
    else           { src = t2; dst = inv2; r = row - NBP; }
    float4 v = reinterpret_cast<const float4*>(src + (size_t)r * ND)[lane];
    float ss = v.x * v.x + v.y * v.y + v.z * v.z + v.w * v.w;
    #pragma unroll
    for (int off = 32; off > 0; off >>= 1)
        ss += __shfl_xor(ss, off, 64);
    if (lane == 0)
        dst[r] = 1.0f / fmaxf(sqrtf(ss), 1e-12f);
}

__device__ __forceinline__ v8bf cvt8(float4 a, float4 b, float s) {
    v8bf v;
    v[0] = (__bf16)(a.x * s); v[1] = (__bf16)(a.y * s);
    v[2] = (__bf16)(a.z * s); v[3] = (__bf16)(a.w * s);
    v[4] = (__bf16)(b.x * s); v[5] = (__bf16)(b.y * s);
    v[6] = (__bf16)(b.z * s); v[7] = (__bf16)(b.w * s);
    return v;
}

__global__ __launch_bounds__(256, 2)
void filip_mfma(const float* __restrict__ t1, const float* __restrict__ t2,
                const float* __restrict__ inv1, const float* __restrict__ inv2,
                float* __restrict__ sim12)
{
    __shared__ unsigned short Asb[BM * BK];
    __shared__ unsigned short Bsb[BN * BK];
    __shared__ float rmx[2][BM];

    const int bRow = blockIdx.x;
    const int b2   = blockIdx.y;
    const int tid  = threadIdx.x;
    const int lane = tid & 63, wave = tid >> 6;
    const int wr = wave >> 1, wc = wave & 1;
    const int ln = lane & 31, hi = lane >> 5;

    const float* Abase = t1 + (size_t)bRow * BM * ND;
    const float* Bbase = t2 + (size_t)b2 * NP * ND;

    f32x16 acc[2][4];
    #pragma unroll
    for (int mt = 0; mt < 2; ++mt)
        #pragma unroll
        for (int nt = 0; nt < 4; ++nt)
            #pragma unroll
            for (int r = 0; r < 16; ++r) acc[mt][nt][r] = 0.0f;

    for (int kc = 0; kc < 4; ++kc) {
        __syncthreads();
        #pragma unroll
        for (int i = 0; i < 4; ++i) {
            int flat = (i * 256 + tid) * 8;
            int r = flat >> 6, k0 = flat & 63;
            const float* gp = Abase + (size_t)r * ND + kc * BK + k0;
            float4 f0 = *reinterpret_cast<const float4*>(gp);
            float4 f1 = *reinterpret_cast<const float4*>(gp + 4);
            float s = inv1[bRow * BM + r];
            v8bf v = cvt8(f0, f1, s);
            int off = r * 128 + ((k0 * 2) ^ ((r & 7) << 4));
            *reinterpret_cast<v8bf*>(reinterpret_cast<char*>(Asb) + off) = v;
        }
        #pragma unroll
        for (int i = 0; i < 8; ++i) {
            int flat = (i * 256 + tid) * 8;
            int r = flat >> 6, k0 = flat & 63;
            v8bf v;
            if (r < NP) {
                const float* gp = Bbase + (size_t)r * ND + kc * BK + k0;
                float4 f0 = *reinterpret_cast<const float4*>(gp);
                float4 f1 = *reinterpret_cast<const float4*>(gp + 4);
                float s = inv2[b2 * NP + r];
                v = cvt8(f0, f1, s);
            } else {
                #pragma unroll
                for (int j = 0; j < 8; ++j) v[j] = (__bf16)0.0f;
            }
            int off = r * 128 + ((k0 * 2) ^ ((r & 7) << 4));
            *reinterpret_cast<v8bf*>(reinterpret_cast<char*>(Bsb) + off) = v;
        }
        __syncthreads();
        #pragma unroll
        for (int ks = 0; ks < 4; ++ks) {
            const int kb = ks * 32 + hi * 16;
            v8bf af[2], bfr[4];
            #pragma unroll
            for (int mt = 0; mt < 2; ++mt) {
                int r = wr * 64 + mt * 32 + ln;
                af[mt] = *reinterpret_cast<const v8bf*>(
                    reinterpret_cast<const char*>(Asb) + r * 128 + (kb ^ ((r & 7) << 4)));
            }
            #pragma unroll
            for (int nt = 0; nt < 4; ++nt) {
                int c = wc * 128 + nt * 32 + ln;
                bfr[nt] = *reinterpret_cast<const v8bf*>(
                    reinterpret_cast<const char*>(Bsb) + c * 128 + (kb ^ ((c & 7) << 4)));
            }
            #pragma unroll
            for (int mt = 0; mt < 2; ++mt)
                #pragma unroll
                for (int nt = 0; nt < 4; ++nt)
                    acc[mt][nt] = __builtin_amdgcn_mfma_f32_32x32x16_bf16(
                        af[mt], bfr[nt], acc[mt][nt], 0, 0, 0);
        }
    }

    #pragma unroll
    for (int mt = 0; mt < 2; ++mt) {
        float t[16];
        #pragma unroll
        for (int r = 0; r < 16; ++r) {
            float m = fmaxf(fmaxf(acc[mt][0][r], acc[mt][1][r]),
                            fmaxf(acc[mt][2][r], acc[mt][3][r]));
            #pragma unroll
            for (int off = 1; off <= 16; off <<= 1)
                m = fmaxf(m, __shfl_xor(m, off, 64));
            t[r] = m;
        }
        if (ln == 0) {
            #pragma unroll
            for (int r = 0; r < 16; ++r) {
                int row = wr * 64 + mt * 32 + (r & 3) + 8 * (r >> 2) + 4 * hi;
                rmx[wc][row] = t[r];
            }
        }
    }
    __syncthreads();
    if (tid < BM) {
        float m = fmaxf(rmx[0][tid], rmx[1][tid]);
        int grow = bRow * BM + tid;
        int b1 = grow / NP;
        int fb = (bRow * BM) / NP;
        float v0 = (b1 == fb) ? m : 0.0f;
        float v1 = (b1 != fb) ? m : 0.0f;
        #pragma unroll
        for (int off = 1; off < 64; off <<= 1) {
            v0 += __shfl_xor(v0, off, 64);
            v1 += __shfl_xor(v1, off, 64);
        }
        if (lane == 0) {
            atomicAdd(&sim12[fb * NB + b2], v0);
            int lb = (bRow * BM + BM - 1) / NP;
            if (lb != fb) atomicAdd(&sim12[lb * NB + b2], v1);
        }
    }
}

__global__ __launch_bounds__(256)
void filip_diag(const float* __restrict__ t1, const float* __restrict__ t2,
                const float* __restrict__ inv1, const float* __restrict__ inv2,
                float* __restrict__ out)
{
    const int b = blockIdx.x;
    const int tid = threadIdx.x;
    const int tx = tid & 15, ty = tid >> 4;

    __shared__ float As2[16][209];
    __shared__ float Bs2[16][65];
    __shared__ float colV[16][65];
    __shared__ int   colI[16][65];

    const float* Ap = t1 + (size_t)b * NP * ND;
    const float* Bp = t2 + (size_t)b * NP * ND;
    const float* ia = inv1 + b * NP;
    const float* ib = inv2 + b * NP;

    float rmax[13];
    int   ridx[13];
    #pragma unroll
    for (int m = 0; m < 13; ++m) { rmax[m] = -3.0e38f; ridx[m] = 1 << 30; }

    for (int tile = 0; tile < 4; ++tile) {
        float acc[13][4];
        #pragma unroll
        for (int m = 0; m < 13; ++m)
            #pragma unroll
            for (int n = 0; n < 4; ++n) acc[m][n] = 0.0f;

        for (int kk = 0; kk < 16; ++kk) {
            __syncthreads();
            #pragma unroll
            for (int i = 0; i < 13; ++i) {
                int e = tid + 256 * i;
                int p1 = e >> 4, k = e & 15;
                float v = 0.0f;
                if (p1 < NP) v = Ap[p1 * ND + kk * 16 + k] * ia[p1];
                As2[k][p1] = v;
            }
            #pragma unroll
            for (int i = 0; i < 4; ++i) {
                int e = tid + 256 * i;
                int pl = e >> 4, k = e & 15;
                int p2 = tile * 64 + pl;
                float v = 0.0f;
                if (p2 < NP) v = Bp[p2 * ND + kk * 16 + k] * ib[p2];
                Bs2[k][pl] = v;
            }
            __syncthreads();
            #pragma unroll 4
            for (int k = 0; k < 16; ++k) {
                float a[13], bq[4];
                #pragma unroll
                for (int m = 0; m < 13; ++m) a[m] = As2[k][ty + 16 * m];
                #pragma unroll
                for (int n = 0; n < 4; ++n) bq[n] = Bs2[k][tx + 16 * n];
                #pragma unroll
                for (int m = 0; m < 13; ++m)
                    #pragma unroll
                    for (int n = 0; n < 4; ++n)
                        acc[m][n] = fmaf(a[m], bq[n], acc[m][n]);
            }
        }

        #pragma unroll
        for (int n = 0; n < 4; ++n) {
            int c = tile * 64 + tx + 16 * n;
            if (c < NP) {
                #pragma unroll
                for (int m = 0; m < 13; ++m) {
                    float v = acc[m][n];
                    if (v > rmax[m] || (v == rmax[m] && c < ridx[m])) {
                        rmax[m] = v; ridx[m] = c;
                    }
                }
            }
        }

        #pragma unroll
        for (int n = 0; n < 4; ++n) {
            float bv = -3.0e38f; int bi = 1 << 30;
            #pragma unroll
            for (int m = 0; m < 13; ++m) {
                int row = ty + 16 * m;
                if (row < NP) {
                    float v = acc[m][n];
                    if (v > bv || (v == bv && row < bi)) { bv = v; bi = row; }
                }
            }
            colV[ty][tx + 16 * n] = bv;
            colI[ty][tx + 16 * n] = bi;
        }
        __syncthreads();
        if (tid < 64) {
            int c = tile * 64 + tid;
            if (c < NP) {
                float bv = -3.0e38f; int bi = 1 << 30;
                #pragma unroll
                for (int y = 0; y < 16; ++y) {
                    float v = colV[y][tid]; int i2 = colI[y][tid];
                    if (v > bv || (v == bv && i2 < bi)) { bv = v; bi = i2; }
                }
                out[1 + NBP + b * NP + c] = (float)bi;
            }
        }
        __syncthreads();
    }

    #pragma unroll
    for (int m = 0; m < 13; ++m) {
        float v = rmax[m]; int ix = ridx[m];
        #pragma unroll
        for (int off = 1; off < 16; off <<= 1) {
            float ov = __shfl_xor(v, off, 16);
            int   oi = __shfl_xor(ix, off, 16);
            if (ov > v || (ov == v && oi < ix)) { v = ov; ix = oi; }
        }
        rmax[m] = v; ridx[m] = ix;
    }
    if (tx == 0) {
        #pragma unroll
        for (int m = 0; m < 13; ++m) {
            int row = ty + 16 * m;
            if (row < NP) out[1 + b * NP + row] = (float)ridx[m];
        }
    }
}

// ---------------------------------------------------------------------------
extern "C" void kernel_launch(void* const* d_in, const int* in_sizes, int n_in,
                              void* d_out, int out_size, void* d_ws, size_t ws_size,
                              hipStream_t stream) {
    const float* t1 = (const float*)d_in[0];
    const float* t2 = (const float*)d_in[1];
    float* out = (float*)d_out;
    float* ws  = (float*)d_ws;

    float* inv1  = ws;
    float* inv2  = ws + NBP;
    float* sim12 = ws + 2 * NBP;

    if (ws_size >= (size_t)WS_NEED) {
        __bf16* t1bf = (__bf16*)((char*)d_ws + WS_T1BF);
        __bf16* t2bf = (__bf16*)((char*)d_ws + WS_T2BF);
        unsigned long long* parts = (unsigned long long*)((char*)d_ws + WS_PARTS);

        filip_prep<<<NBP + NB * 256, 64, 0, stream>>>(t1, t2, inv1, inv2, sim12, t1bf, t2bf);
        filip_mfma2<<<dim3(98, NB), 256, 0, stream>>>(t1bf, t2bf, sim12);
        filip_diag4<<<dim3(4, NB), 256, 0, stream>>>(t1, t2, inv1, inv2, parts, out);
        filip_fin<<<49, 256, 0, stream>>>(parts, out);
        filip_loss<<<1, 64, 0, stream>>>(sim12, out);
    } else {
        filip_norms<<<2 * NBP, 64, 0, stream>>>(t1, t2, inv1, inv2, sim12);
        filip_mfma<<<dim3(98, NB), 256, 0, stream>>>(t1, t2, inv1, inv2, sim12);
        filip_diag<<<NB, 256, 0, stream>>>(t1, t2, inv1, inv2, out);
        filip_loss<<<1, 64, 0, stream>>>(sim12, out);
    }
}